// Round 6
// baseline (978.769 us; speedup 1.0000x reference)
//
#include <hip/hip_runtime.h>
#include <hip/hip_bf16.h>
#include <cstdint>
#include <cstddef>

// MoE: T=2048 tokens, D=2048, INNER=5632, E=8, top-2 routing (sparse == dense ref).

#define TOKS  2048
#define DIMSZ 2048
#define INNER 5632
#define NEXP  8

typedef __attribute__((ext_vector_type(8))) short short8;
typedef __attribute__((ext_vector_type(4))) float f32x4;

__device__ __forceinline__ unsigned short f2bf(float f) {
  __hip_bfloat16 b = __float2bfloat16(f);
  return __builtin_bit_cast(unsigned short, b);
}

__device__ __forceinline__ short8 pack8(float4 a, float4 b) {
  short8 s;
  s[0] = (short)f2bf(a.x); s[1] = (short)f2bf(a.y);
  s[2] = (short)f2bf(a.z); s[3] = (short)f2bf(a.w);
  s[4] = (short)f2bf(b.x); s[5] = (short)f2bf(b.y);
  s[6] = (short)f2bf(b.z); s[7] = (short)f2bf(b.w);
  return s;
}

// async global->LDS, 16B/lane; dst is wave-uniform base (HW adds lane*16)
__device__ __forceinline__ void gload16(const unsigned short* src, short8* dst) {
  __builtin_amdgcn_global_load_lds(
      (const __attribute__((address_space(1))) void*)src,
      (__attribute__((address_space(3))) void*)dst, 16, 0, 0);
}

// counted waits (T4): wait until <= N vector-memory ops outstanding
#define VMCNT(n) asm volatile("s_waitcnt vmcnt(" #n ")" ::: "memory")

// ---------------- router -----------------------------------------------------
__global__ void __launch_bounds__(64)
router_kernel(const float* __restrict__ x, const float* __restrict__ gw,
              int* __restrict__ sel, float* __restrict__ wts) {
  const int t = blockIdx.x;
  const int l = threadIdx.x;
  const float* xr = x + (size_t)t * DIMSZ;
  float xv[32];
#pragma unroll
  for (int i = 0; i < 32; ++i) xv[i] = xr[l + 64 * i];
  float lg[NEXP];
#pragma unroll
  for (int e = 0; e < NEXP; ++e) {
    const float* gr = gw + e * DIMSZ;
    float s = 0.f;
#pragma unroll
    for (int i = 0; i < 32; ++i) s += xv[i] * gr[l + 64 * i];
#pragma unroll
    for (int off = 32; off > 0; off >>= 1) s += __shfl_down(s, off, 64);
    lg[e] = s;
  }
  if (l == 0) {
    float m = lg[0];
#pragma unroll
    for (int e = 1; e < NEXP; ++e) m = fmaxf(m, lg[e]);
    float p[NEXP];
#pragma unroll
    for (int e = 0; e < NEXP; ++e) p[e] = __expf(lg[e] - m);
    int i1 = 0;
#pragma unroll
    for (int e = 1; e < NEXP; ++e) if (p[e] > p[i1]) i1 = e;
    int i2 = (i1 == 0) ? 1 : 0;
#pragma unroll
    for (int e = 0; e < NEXP; ++e) if (e != i1 && p[e] > p[i2]) i2 = e;
    float den = p[i1] + p[i2];
    sel[2 * t] = i1; sel[2 * t + 1] = i2;
    wts[2 * t] = p[i1] / den; wts[2 * t + 1] = p[i2] / den;
  }
}

// ---- compaction -------------------------------------------------------------
__global__ void __launch_bounds__(512)
compact_kernel(const int* __restrict__ sel, const float* __restrict__ wts,
               int* __restrict__ cnt, int* __restrict__ offs,
               int* __restrict__ tok, float* __restrict__ twt) {
  const int w = threadIdx.x >> 6;
  const int l = threadIdx.x & 63;
  int c = 0;
  for (int base = 0; base < 2 * TOKS; base += 64) {
    int s = base + l;
    bool m = (sel[s] == w);
    unsigned long long mask = __ballot(m);
    int pre = __popcll(mask & ((1ull << l) - 1ull));
    if (m) {
      tok[w * TOKS + c + pre] = s >> 1;
      twt[w * TOKS + c + pre] = wts[s];
    }
    c += __popcll(mask);
  }
  if (l == 0) cnt[w] = c;
  __syncthreads();
  if (threadIdx.x == 0) {
    int acc = 0;
    for (int e = 0; e < NEXP; ++e) { offs[e] = acc; acc += cnt[e]; }
  }
}

// ---------------- fp32 -> bf16 converters ------------------------------------
__global__ void __launch_bounds__(256)
cvtx_kernel(const float* __restrict__ x, unsigned short* __restrict__ xbf) {
  const int i = blockIdx.x * 256 + threadIdx.x;
  const float4* src = (const float4*)x;
  ((short8*)xbf)[i] = pack8(src[2 * i], src[2 * i + 1]);
}

__global__ void __launch_bounds__(256)
cvtw_kernel(const float* __restrict__ src, unsigned short* __restrict__ dst, int n8) {
  const int stride = gridDim.x * 256;
  for (int i = blockIdx.x * 256 + threadIdx.x; i < n8; i += stride) {
    const float4* s = (const float4*)src + 2 * (size_t)i;
    ((short8*)dst)[i] = pack8(s[0], s[1]);
  }
}

// ------- GEMM1 (bf16 weights): h = silu(x·w1^T) * (x·w3^T) ------------------
// 128(M)x64(N), BK=64, 4 waves (2Mx2N). Double-buffered LDS with COUNTED
// vmcnt + raw s_barrier (T3/T4): stage(k+1) stays in flight across the
// barrier; compute(k) waits only on stage(k) (vmcnt(8) = the 8 newer loads
// may remain outstanding). XCD-bijective remap (R5-verified).
__global__ void __launch_bounds__(256, 2)
gemm1_bf(const unsigned short* __restrict__ xbf,
         const unsigned short* __restrict__ w1b, const unsigned short* __restrict__ w3b,
         const int* __restrict__ cnt, const int* __restrict__ offs,
         const int* __restrict__ tok, unsigned short* __restrict__ h) {
  const int NWG   = (INNER / 64) * NEXP * 16;
  const int CHUNK = NWG / 8;
  const int lid = (blockIdx.x & 7) * CHUNK + (blockIdx.x >> 3);
  const int my = lid & 15;             // M-slot (panel-mates adjacent in lid)
  const int e  = (lid >> 4) & 7;
  const int bx = lid >> 7;             // 0..87 N-panel
  const int n_e = cnt[e];
  if (n_e == 0 || my * 128 >= n_e) return;
  const int n0 = bx * 64;
  const int tid = threadIdx.x;
  const int lane = tid & 63;
  const int wid = tid >> 6;
  const int wm = wid >> 1, wn = wid & 1;

  __shared__ short8 As[2][1024];   // 2 x 16KB
  __shared__ short8 B1s[2][512];   // 2 x 8KB
  __shared__ short8 B3s[2][512];   // total 64KB -> 2 blocks/CU

  // A: per-lane pre-swizzled source (g ^ row&7), linear LDS dest
  const unsigned short* aptr[4];
#pragma unroll
  for (int i = 0; i < 4; ++i) {
    int sl = i * 256 + wid * 64 + lane;
    int row = sl >> 3, g = sl & 7;
    int ri = my * 128 + row; if (ri >= n_e) ri = n_e - 1;
    int tkn = tok[e * TOKS + ri];
    aptr[i] = xbf + (size_t)tkn * DIMSZ + ((g ^ (row & 7)) * 8);
  }
  const unsigned short* b1ptr[2]; const unsigned short* b3ptr[2];
#pragma unroll
  for (int i = 0; i < 2; ++i) {
    int sl = i * 256 + wid * 64 + lane;
    int row = sl >> 3, g = sl & 7;
    size_t off = (size_t)e * INNER * DIMSZ + (size_t)(n0 + row) * DIMSZ + (g ^ (row & 7)) * 8;
    b1ptr[i] = w1b + off;
    b3ptr[i] = w3b + off;
  }

  f32x4 acc1[4][2] = {};
  f32x4 acc3[4][2] = {};
  const int NK = DIMSZ / 64;  // 32

  // prologue: stage k=0 into buf 0 (8 VMEM ops/thread)
#pragma unroll
  for (int i = 0; i < 4; ++i) gload16(aptr[i], &As[0][i * 256 + wid * 64]);
#pragma unroll
  for (int i = 0; i < 2; ++i) {
    gload16(b1ptr[i], &B1s[0][i * 256 + wid * 64]);
    gload16(b3ptr[i], &B3s[0][i * 256 + wid * 64]);
  }

  int cur = 0;
  for (int k = 0; k < NK; ++k) {
    const int nxt = cur ^ 1;
    if (k + 1 < NK) {
      const int k1 = (k + 1) * 64;
#pragma unroll
      for (int i = 0; i < 4; ++i) gload16(aptr[i] + k1, &As[nxt][i * 256 + wid * 64]);
#pragma unroll
      for (int i = 0; i < 2; ++i) {
        gload16(b1ptr[i] + k1, &B1s[nxt][i * 256 + wid * 64]);
        gload16(b3ptr[i] + k1, &B3s[nxt][i * 256 + wid * 64]);
      }
      VMCNT(8);        // stage(k) landed; stage(k+1)'s 8 loads stay in flight
    } else {
      VMCNT(0);        // final tile: drain
    }
    __builtin_amdgcn_s_barrier();   // publish all waves' stage(k)
#pragma unroll
    for (int ks = 0; ks < 2; ++ks) {
      const int kg = ks * 4 + (lane >> 4);
      short8 af[4], b1f[2], b3f[2];
#pragma unroll
      for (int m = 0; m < 4; ++m) {
        int row = wm * 64 + m * 16 + (lane & 15);
        af[m] = As[cur][row * 8 + (kg ^ (row & 7))];
      }
#pragma unroll
      for (int n = 0; n < 2; ++n) {
        int row = wn * 32 + n * 16 + (lane & 15);
        int idx = row * 8 + (kg ^ (row & 7));
        b1f[n] = B1s[cur][idx];
        b3f[n] = B3s[cur][idx];
      }
#pragma unroll
      for (int m = 0; m < 4; ++m)
#pragma unroll
        for (int n = 0; n < 2; ++n) {
          acc1[m][n] = __builtin_amdgcn_mfma_f32_16x16x32_bf16(af[m], b1f[n], acc1[m][n], 0, 0, 0);
          acc3[m][n] = __builtin_amdgcn_mfma_f32_16x16x32_bf16(af[m], b3f[n], acc3[m][n], 0, 0, 0);
        }
    }
    __builtin_amdgcn_s_barrier();   // all reads of buf[cur] done before overwrite
    cur = nxt;
  }

  const int obase = offs[e];
#pragma unroll
  for (int m = 0; m < 4; ++m)
#pragma unroll
    for (int r = 0; r < 4; ++r) {
      int i = my * 128 + wm * 64 + m * 16 + (lane >> 4) * 4 + r;
      if (i < n_e) {
        unsigned short* hp = h + (size_t)(obase + i) * INNER + n0 + wn * 32 + (lane & 15);
#pragma unroll
        for (int n = 0; n < 2; ++n) {
          float v1 = acc1[m][n][r];
          float v3 = acc3[m][n][r];
          float hv = __fdividef(v1, 1.f + __expf(-v1)) * v3;
          hp[n * 16] = f2bf(hv);
        }
      }
    }
}

// ------- GEMM2 (bf16 weights): out[t] += wt * (h · w2^T) --------------------
// 128x128, BK=64, 4 waves (2x2). Same counted-vmcnt double-buffer.
__global__ void __launch_bounds__(256, 2)
gemm2_bf(const unsigned short* __restrict__ h, const unsigned short* __restrict__ w2b,
         const int* __restrict__ cnt, const int* __restrict__ offs,
         const int* __restrict__ tok, const float* __restrict__ twt,
         float* __restrict__ out) {
  const int NWG   = (DIMSZ / 128) * NEXP * 16;   // 2048
  const int CHUNK = NWG / 8;
  const int lid = (blockIdx.x & 7) * CHUNK + (blockIdx.x >> 3);
  const int my = lid & 15;
  const int e  = (lid >> 4) & 7;
  const int bx = lid >> 7;             // 0..15
  const int n_e = cnt[e];
  if (n_e == 0 || my * 128 >= n_e) return;
  const int n0 = bx * 128;
  const int tid = threadIdx.x;
  const int lane = tid & 63;
  const int wid = tid >> 6;
  const int wm = wid >> 1, wn = wid & 1;
  const int obase = offs[e];

  __shared__ short8 As[2][1024];
  __shared__ short8 Bs[2][1024];   // total 64KB -> 2 blocks/CU

  const unsigned short* aptr[4];
#pragma unroll
  for (int i = 0; i < 4; ++i) {
    int sl = i * 256 + wid * 64 + lane;
    int row = sl >> 3, g = sl & 7;
    int ri = my * 128 + row; if (ri >= n_e) ri = n_e - 1;
    aptr[i] = h + (size_t)(obase + ri) * INNER + ((g ^ (row & 7)) * 8);
  }
  const unsigned short* bptr[4];
#pragma unroll
  for (int i = 0; i < 4; ++i) {
    int sl = i * 256 + wid * 64 + lane;
    int row = sl >> 3, g = sl & 7;
    bptr[i] = w2b + (size_t)e * DIMSZ * INNER + (size_t)(n0 + row) * INNER + (g ^ (row & 7)) * 8;
  }

  f32x4 acc[4][4] = {};
  const int NK = INNER / 64;  // 88

  // prologue: stage k=0 (8 VMEM ops/thread)
#pragma unroll
  for (int i = 0; i < 4; ++i) {
    gload16(aptr[i], &As[0][i * 256 + wid * 64]);
    gload16(bptr[i], &Bs[0][i * 256 + wid * 64]);
  }

  int cur = 0;
  for (int k = 0; k < NK; ++k) {
    const int nxt = cur ^ 1;
    if (k + 1 < NK) {
      const int k1 = (k + 1) * 64;
#pragma unroll
      for (int i = 0; i < 4; ++i) {
        gload16(aptr[i] + k1, &As[nxt][i * 256 + wid * 64]);
        gload16(bptr[i] + k1, &Bs[nxt][i * 256 + wid * 64]);
      }
      VMCNT(8);
    } else {
      VMCNT(0);
    }
    __builtin_amdgcn_s_barrier();
#pragma unroll
    for (int ks = 0; ks < 2; ++ks) {
      const int kg = ks * 4 + (lane >> 4);
      short8 af[4], bf[4];
#pragma unroll
      for (int m = 0; m < 4; ++m) {
        int row = wm * 64 + m * 16 + (lane & 15);
        af[m] = As[cur][row * 8 + (kg ^ (row & 7))];
      }
#pragma unroll
      for (int n = 0; n < 4; ++n) {
        int row = wn * 64 + n * 16 + (lane & 15);
        bf[n] = Bs[cur][row * 8 + (kg ^ (row & 7))];
      }
#pragma unroll
      for (int m = 0; m < 4; ++m)
#pragma unroll
        for (int n = 0; n < 4; ++n)
          acc[m][n] = __builtin_amdgcn_mfma_f32_16x16x32_bf16(af[m], bf[n], acc[m][n], 0, 0, 0);
    }
    __builtin_amdgcn_s_barrier();
    cur = nxt;
  }

#pragma unroll
  for (int m = 0; m < 4; ++m)
#pragma unroll
    for (int r = 0; r < 4; ++r) {
      int i = my * 128 + wm * 64 + m * 16 + (lane >> 4) * 4 + r;
      if (i < n_e) {
        int t = tok[e * TOKS + i];
        float wt = twt[e * TOKS + i];
        float* op = out + (size_t)t * DIMSZ + n0 + wn * 64 + (lane & 15);
#pragma unroll
        for (int n = 0; n < 4; ++n)
          atomicAdd(op + n * 16, acc[m][n][r] * wt);
      }
    }
}

// ======= fallback path (fp32 weights in-kernel cvt) — used if ws small ======
__global__ void __launch_bounds__(256, 2)
gemm1_f32(const unsigned short* __restrict__ xbf,
          const float* __restrict__ w1, const float* __restrict__ w3,
          const int* __restrict__ cnt, const int* __restrict__ offs,
          const int* __restrict__ tok, unsigned short* __restrict__ h) {
  const int e = blockIdx.z;
  const int n_e = cnt[e];
  const int by = blockIdx.y;
  if (n_e == 0 || by * 128 >= n_e) return;
  const int n0 = blockIdx.x * 128;
  const int tid = threadIdx.x;
  const int lane = tid & 63;
  const int wid = tid >> 6;
  const int wm = wid >> 1, wn = wid & 1;

  __shared__ short8 As[1024];
  __shared__ short8 B1s[1024];
  __shared__ short8 B3s[1024];

  const unsigned short* asrc[4];
  int adst[4];
#pragma unroll
  for (int rep = 0; rep < 4; ++rep) {
    int flat = rep * 256 + tid;
    int row = flat >> 3, g = flat & 7;
    int ri = by * 128 + row;
    if (ri >= n_e) ri = n_e - 1;
    int tkn = tok[e * TOKS + ri];
    asrc[rep] = xbf + (size_t)tkn * DIMSZ + g * 8;
    adst[rep] = row * 8 + (g ^ (row & 7));
  }
  const float* w1e = w1 + (size_t)e * INNER * DIMSZ;
  const float* w3e = w3 + (size_t)e * INNER * DIMSZ;
  const float* b1src[2]; const float* b3src[2];
  int bd0[2], bd1[2];
#pragma unroll
  for (int rep = 0; rep < 2; ++rep) {
    int row = rep * 64 + (tid >> 2);
    int gb = (tid & 3) * 2;
    b1src[rep] = w1e + (size_t)(n0 + row) * DIMSZ + gb * 8;
    b3src[rep] = w3e + (size_t)(n0 + row) * DIMSZ + gb * 8;
    bd0[rep] = row * 8 + (gb ^ (row & 7));
    bd1[rep] = row * 8 + ((gb + 1) ^ (row & 7));
  }

  f32x4 acc1[4][4] = {};
  f32x4 acc3[4][4] = {};

#pragma unroll 1
  for (int k0 = 0; k0 < DIMSZ; k0 += 64) {
#pragma unroll
    for (int rep = 0; rep < 4; ++rep)
      As[adst[rep]] = *(const short8*)(asrc[rep] + k0);
#pragma unroll
    for (int rep = 0; rep < 2; ++rep) {
      const float4* p = (const float4*)(b1src[rep] + k0);
      float4 a0 = p[0], a1 = p[1], a2 = p[2], a3 = p[3];
      B1s[bd0[rep]] = pack8(a0, a1);
      B1s[bd1[rep]] = pack8(a2, a3);
      const float4* q = (const float4*)(b3src[rep] + k0);
      float4 c0 = q[0], c1 = q[1], c2 = q[2], c3 = q[3];
      B3s[bd0[rep]] = pack8(c0, c1);
      B3s[bd1[rep]] = pack8(c2, c3);
    }
    __syncthreads();
#pragma unroll
    for (int ks = 0; ks < 2; ++ks) {
      const int kg = ks * 4 + (lane >> 4);
      short8 af[4], b1f[4], b3f[4];
#pragma unroll
      for (int m = 0; m < 4; ++m) {
        int row = wm * 64 + m * 16 + (lane & 15);
        af[m] = As[row * 8 + (kg ^ (row & 7))];
      }
#pragma unroll
      for (int n = 0; n < 4; ++n) {
        int row = wn * 64 + n * 16 + (lane & 15);
        int idx = row * 8 + (kg ^ (row & 7));
        b1f[n] = B1s[idx];
        b3f[n] = B3s[idx];
      }
#pragma unroll
      for (int m = 0; m < 4; ++m)
#pragma unroll
        for (int n = 0; n < 4; ++n) {
          acc1[m][n] = __builtin_amdgcn_mfma_f32_16x16x32_bf16(af[m], b1f[n], acc1[m][n], 0, 0, 0);
          acc3[m][n] = __builtin_amdgcn_mfma_f32_16x16x32_bf16(af[m], b3f[n], acc3[m][n], 0, 0, 0);
        }
    }
    __syncthreads();
  }

  const int obase = offs[e];
#pragma unroll
  for (int m = 0; m < 4; ++m)
#pragma unroll
    for (int r = 0; r < 4; ++r) {
      int i = by * 128 + wm * 64 + m * 16 + (lane >> 4) * 4 + r;
      if (i < n_e) {
        unsigned short* hp = h + (size_t)(obase + i) * INNER + n0 + wn * 64 + (lane & 15);
#pragma unroll
        for (int n = 0; n < 4; ++n) {
          float v1 = acc1[m][n][r];
          float v3 = acc3[m][n][r];
          float hv = __fdividef(v1, 1.f + __expf(-v1)) * v3;
          hp[n * 16] = f2bf(hv);
        }
      }
    }
}

__global__ void __launch_bounds__(256, 2)
gemm2_f32(const unsigned short* __restrict__ h, const float* __restrict__ w2,
          const int* __restrict__ cnt, const int* __restrict__ offs,
          const int* __restrict__ tok, const float* __restrict__ twt,
          float* __restrict__ out) {
  const int e = blockIdx.z;
  const int n_e = cnt[e];
  const int by = blockIdx.y;
  if (n_e == 0 || by * 128 >= n_e) return;
  const int n0 = blockIdx.x * 128;
  const int tid = threadIdx.x;
  const int lane = tid & 63;
  const int wid = tid >> 6;
  const int wm = wid >> 1, wn = wid & 1;
  const int obase = offs[e];

  __shared__ short8 As[1024];
  __shared__ short8 Bs[1024];

  const unsigned short* asrc[4];
  int adst[4];
#pragma unroll
  for (int rep = 0; rep < 4; ++rep) {
    int flat = rep * 256 + tid;
    int row = flat >> 3, g = flat & 7;
    int ri = by * 128 + row;
    if (ri >= n_e) ri = n_e - 1;
    asrc[rep] = h + (size_t)(obase + ri) * INNER + g * 8;
    adst[rep] = row * 8 + (g ^ (row & 7));
  }
  const float* w2e = w2 + (size_t)e * DIMSZ * INNER;
  const float* bsrc[2];
  int bd0[2], bd1[2];
#pragma unroll
  for (int rep = 0; rep < 2; ++rep) {
    int row = rep * 64 + (tid >> 2);
    int gb = (tid & 3) * 2;
    bsrc[rep] = w2e + (size_t)(n0 + row) * INNER + gb * 8;
    bd0[rep] = row * 8 + (gb ^ (row & 7));
    bd1[rep] = row * 8 + ((gb + 1) ^ (row & 7));
  }

  f32x4 acc[4][4] = {};

#pragma unroll 1
  for (int k0 = 0; k0 < INNER; k0 += 64) {
#pragma unroll
    for (int rep = 0; rep < 4; ++rep)
      As[adst[rep]] = *(const short8*)(asrc[rep] + k0);
#pragma unroll
    for (int rep = 0; rep < 2; ++rep) {
      const float4* p = (const float4*)(bsrc[rep] + k0);
      float4 a0 = p[0], a1 = p[1], a2 = p[2], a3 = p[3];
      Bs[bd0[rep]] = pack8(a0, a1);
      Bs[bd1[rep]] = pack8(a2, a3);
    }
    __syncthreads();
#pragma unroll
    for (int ks = 0; ks < 2; ++ks) {
      const int kg = ks * 4 + (lane >> 4);
      short8 af[4], bf[4];
#pragma unroll
      for (int m = 0; m < 4; ++m) {
        int row = wm * 64 + m * 16 + (lane & 15);
        af[m] = As[row * 8 + (kg ^ (row & 7))];
      }
#pragma unroll
      for (int n = 0; n < 4; ++n) {
        int row = wn * 64 + n * 16 + (lane & 15);
        bf[n] = Bs[row * 8 + (kg ^ (row & 7))];
      }
#pragma unroll
      for (int m = 0; m < 4; ++m)
#pragma unroll
        for (int n = 0; n < 4; ++n)
          acc[m][n] = __builtin_amdgcn_mfma_f32_16x16x32_bf16(af[m], bf[n], acc[m][n], 0, 0, 0);
    }
    __syncthreads();
  }

#pragma unroll
  for (int m = 0; m < 4; ++m)
#pragma unroll
    for (int r = 0; r < 4; ++r) {
      int i = by * 128 + wm * 64 + m * 16 + (lane >> 4) * 4 + r;
      if (i < n_e) {
        int t = tok[e * TOKS + i];
        float wt = twt[e * TOKS + i];
        float* op = out + (size_t)t * DIMSZ + n0 + wn * 64 + (lane & 15);
#pragma unroll
        for (int n = 0; n < 4; ++n)
          atomicAdd(op + n * 16, acc[m][n][r] * wt);
      }
    }
}

// ---------------------------------------------------------------------------
extern "C" void kernel_launch(void* const* d_in, const int* in_sizes, int n_in,
                              void* d_out, int out_size, void* d_ws, size_t ws_size,
                              hipStream_t stream) {
  (void)in_sizes; (void)n_in;
  const float* x  = (const float*)d_in[0];
  const float* gw = (const float*)d_in[1];
  const float* w1 = (const float*)d_in[2];
  const float* w2 = (const float*)d_in[3];
  const float* w3 = (const float*)d_in[4];
  float* out = (float*)d_out;

  char* ws = (char*)d_ws;
  int*            sel  = (int*)(ws);
  float*          wts  = (float*)(ws + (16 << 10));
  int*            cnt  = (int*)(ws + (32 << 10));
  int*            offs = (int*)(ws + (32 << 10) + 64);
  int*            tok  = (int*)(ws + (33 << 10));
  float*          twt  = (float*)(ws + (97 << 10));
  unsigned short* xbf  = (unsigned short*)(ws + (1 << 20));   // 8.4 MB
  unsigned short* h    = (unsigned short*)(ws + (16 << 20));  // 46.2 MB

  const size_t WELEM = (size_t)NEXP * INNER * DIMSZ;          // 92,274,688
  const size_t WB    = WELEM * 2;                             // 184,549,376 B
  unsigned short* w1bf = (unsigned short*)(ws + (64ull << 20));        // also w2bf later
  unsigned short* w3bf = (unsigned short*)(ws + (64ull << 20) + WB);
  const size_t NEED = (64ull << 20) + 2 * WB;                 // 436,207,616

  hipMemsetAsync(out, 0, (size_t)out_size * sizeof(float), stream);
  cvtx_kernel<<<2048, 256, 0, stream>>>(x, xbf);
  router_kernel<<<TOKS, 64, 0, stream>>>(x, gw, sel, wts);
  compact_kernel<<<1, 512, 0, stream>>>(sel, wts, cnt, offs, tok, twt);

  if (ws_size >= NEED) {
    const int n8 = (int)(WELEM / 8);
    cvtw_kernel<<<4096, 256, 0, stream>>>(w1, w1bf, n8);
    cvtw_kernel<<<4096, 256, 0, stream>>>(w3, w3bf, n8);
    gemm1_bf<<<(INNER / 64) * 16 * NEXP, 256, 0, stream>>>(
        xbf, w1bf, w3bf, cnt, offs, tok, h);
    cvtw_kernel<<<4096, 256, 0, stream>>>(w2, w1bf, n8);   // reuse slot
    gemm2_bf<<<(DIMSZ / 128) * 16 * NEXP, 256, 0, stream>>>(
        h, w1bf, cnt, offs, tok, twt, out);
  } else {
    gemm1_f32<<<dim3(INNER / 128, TOKS / 128, NEXP), 256, 0, stream>>>(
        xbf, w1, w3, cnt, offs, tok, h);
    gemm2_f32<<<dim3(DIMSZ / 128, TOKS / 128, NEXP), 256, 0, stream>>>(
        h, w2, cnt, offs, tok, twt, out);
  }
}

// Round 7
// 759.696 us; speedup vs baseline: 1.2884x; 1.2884x over previous
//
#include <hip/hip_runtime.h>
#include <hip/hip_bf16.h>
#include <cstdint>
#include <cstddef>

// MoE: T=2048 tokens, D=2048, INNER=5632, E=8, top-2 routing (sparse == dense ref).

#define TOKS  2048
#define DIMSZ 2048
#define INNER 5632
#define NEXP  8

typedef __attribute__((ext_vector_type(8))) short short8;
typedef __attribute__((ext_vector_type(4))) float f32x4;

__device__ __forceinline__ unsigned short f2bf(float f) {
  __hip_bfloat16 b = __float2bfloat16(f);
  return __builtin_bit_cast(unsigned short, b);
}

__device__ __forceinline__ short8 pack8(float4 a, float4 b) {
  short8 s;
  s[0] = (short)f2bf(a.x); s[1] = (short)f2bf(a.y);
  s[2] = (short)f2bf(a.z); s[3] = (short)f2bf(a.w);
  s[4] = (short)f2bf(b.x); s[5] = (short)f2bf(b.y);
  s[6] = (short)f2bf(b.z); s[7] = (short)f2bf(b.w);
  return s;
}

// async global->LDS, 16B/lane; dst is wave-uniform base (HW adds lane*16)
__device__ __forceinline__ void gload16(const unsigned short* src, short8* dst) {
  __builtin_amdgcn_global_load_lds(
      (const __attribute__((address_space(1))) void*)src,
      (__attribute__((address_space(3))) void*)dst, 16, 0, 0);
}
__device__ __forceinline__ void gload16f(const float* src, float4* dst) {
  __builtin_amdgcn_global_load_lds(
      (const __attribute__((address_space(1))) void*)src,
      (__attribute__((address_space(3))) void*)dst, 16, 0, 0);
}

// ---------------- router -----------------------------------------------------
__global__ void __launch_bounds__(64)
router_kernel(const float* __restrict__ x, const float* __restrict__ gw,
              int* __restrict__ sel, float* __restrict__ wts) {
  const int t = blockIdx.x;
  const int l = threadIdx.x;
  const float* xr = x + (size_t)t * DIMSZ;
  float xv[32];
#pragma unroll
  for (int i = 0; i < 32; ++i) xv[i] = xr[l + 64 * i];
  float lg[NEXP];
#pragma unroll
  for (int e = 0; e < NEXP; ++e) {
    const float* gr = gw + e * DIMSZ;
    float s = 0.f;
#pragma unroll
    for (int i = 0; i < 32; ++i) s += xv[i] * gr[l + 64 * i];
#pragma unroll
    for (int off = 32; off > 0; off >>= 1) s += __shfl_down(s, off, 64);
    lg[e] = s;
  }
  if (l == 0) {
    float m = lg[0];
#pragma unroll
    for (int e = 1; e < NEXP; ++e) m = fmaxf(m, lg[e]);
    float p[NEXP];
#pragma unroll
    for (int e = 0; e < NEXP; ++e) p[e] = __expf(lg[e] - m);
    int i1 = 0;
#pragma unroll
    for (int e = 1; e < NEXP; ++e) if (p[e] > p[i1]) i1 = e;
    int i2 = (i1 == 0) ? 1 : 0;
#pragma unroll
    for (int e = 0; e < NEXP; ++e) if (e != i1 && p[e] > p[i2]) i2 = e;
    float den = p[i1] + p[i2];
    sel[2 * t] = i1; sel[2 * t + 1] = i2;
    wts[2 * t] = p[i1] / den; wts[2 * t + 1] = p[i2] / den;
  }
}

// ---- compaction -------------------------------------------------------------
__global__ void __launch_bounds__(512)
compact_kernel(const int* __restrict__ sel, const float* __restrict__ wts,
               int* __restrict__ cnt, int* __restrict__ offs,
               int* __restrict__ tok, float* __restrict__ twt) {
  const int w = threadIdx.x >> 6;
  const int l = threadIdx.x & 63;
  int c = 0;
  for (int base = 0; base < 2 * TOKS; base += 64) {
    int s = base + l;
    bool m = (sel[s] == w);
    unsigned long long mask = __ballot(m);
    int pre = __popcll(mask & ((1ull << l) - 1ull));
    if (m) {
      tok[w * TOKS + c + pre] = s >> 1;
      twt[w * TOKS + c + pre] = wts[s];
    }
    c += __popcll(mask);
  }
  if (l == 0) cnt[w] = c;
  __syncthreads();
  if (threadIdx.x == 0) {
    int acc = 0;
    for (int e = 0; e < NEXP; ++e) { offs[e] = acc; acc += cnt[e]; }
  }
}

// ---------------- x fp32 -> bf16 ---------------------------------------------
__global__ void __launch_bounds__(256)
cvtx_kernel(const float* __restrict__ x, unsigned short* __restrict__ xbf) {
  const int i = blockIdx.x * 256 + threadIdx.x;
  const float4* src = (const float4*)x;
  ((short8*)xbf)[i] = pack8(src[2 * i], src[2 * i + 1]);
}

// ------- GEMM1 (direct fp32 weights): h = silu(x·w1^T) * (x·w3^T) -----------
// 128(M)x64(N), BK=64, 4 waves (2Mx2N). R5-verified m97 single-buffer
// 2-barrier loop + XCD-bijective remap. B staged fp32 via global_load_lds
// (16-group XOR swizzle), converted to bf16 at fragment load (cvt_pk on the
// VALU pipe overlaps MFMA). Tail blocks (bid >= NWG) convert w2 -> w2bf so
// gemm2's weight conversion hides under gemm1's BW slack.
__global__ void __launch_bounds__(256, 3)
gemm1_fw(const unsigned short* __restrict__ xbf,
         const float* __restrict__ w1, const float* __restrict__ w3,
         const float* __restrict__ w2, unsigned short* __restrict__ w2bf,
         const int* __restrict__ cnt, const int* __restrict__ offs,
         const int* __restrict__ tok, unsigned short* __restrict__ h) {
  const int NWG   = (INNER / 64) * NEXP * 16;   // 11264
  const int tid = threadIdx.x;

  if ((int)blockIdx.x >= NWG) {                 // ---- fused w2 fp32->bf16 ----
    const int b = blockIdx.x - NWG;             // 0..2047
    const int n8 = (int)(((size_t)NEXP * DIMSZ * INNER) / 8);  // 11,534,336
    for (int i = b * 256 + tid; i < n8; i += 2048 * 256) {
      const float4* s = (const float4*)w2 + 2 * (size_t)i;
      ((short8*)w2bf)[i] = pack8(s[0], s[1]);
    }
    return;
  }

  const int CHUNK = NWG / 8;
  const int lid = (blockIdx.x & 7) * CHUNK + (blockIdx.x >> 3);
  const int my = lid & 15;             // M-slot (panel-mates adjacent in lid)
  const int e  = (lid >> 4) & 7;
  const int bx = lid >> 7;             // 0..87 N-panel
  const int n_e = cnt[e];
  if (n_e == 0 || my * 128 >= n_e) return;
  const int n0 = bx * 64;
  const int lane = tid & 63;
  const int wid = tid >> 6;
  const int wm = wid >> 1, wn = wid & 1;

  __shared__ short8 As[1024];    // 128 rows x 8 bf16-groups (16KB)
  __shared__ float4 B1s[1024];   // 64 rows x 16 f32-groups (16KB)
  __shared__ float4 B3s[1024];   // total 48KB -> 3 blocks/CU

  // A: per-lane pre-swizzled source (g ^ row&7), linear LDS dest (R5-verified)
  const unsigned short* aptr[4];
#pragma unroll
  for (int i = 0; i < 4; ++i) {
    int sl = i * 256 + wid * 64 + lane;
    int row = sl >> 3, g = sl & 7;
    int ri = my * 128 + row; if (ri >= n_e) ri = n_e - 1;
    int tkn = tok[e * TOKS + ri];
    aptr[i] = xbf + (size_t)tkn * DIMSZ + ((g ^ (row & 7)) * 8);
  }
  // B fp32: 64 rows x 16 groups of 4 floats; source col-group = gg ^ (row&15)
  const float* b1p[4]; const float* b3p[4];
#pragma unroll
  for (int i = 0; i < 4; ++i) {
    int sl = i * 256 + wid * 64 + lane;
    int row = sl >> 4, gg = sl & 15;
    size_t off = (size_t)e * INNER * DIMSZ + (size_t)(n0 + row) * DIMSZ
               + ((gg ^ (row & 15)) * 4);
    b1p[i] = w1 + off;
    b3p[i] = w3 + off;
  }

  f32x4 acc1[4][2] = {};
  f32x4 acc3[4][2] = {};

  for (int k0 = 0; k0 < DIMSZ; k0 += 64) {
#pragma unroll
    for (int i = 0; i < 4; ++i) gload16(aptr[i] + k0, &As[i * 256 + wid * 64]);
#pragma unroll
    for (int i = 0; i < 4; ++i) {
      gload16f(b1p[i] + k0, &B1s[i * 256 + wid * 64]);
      gload16f(b3p[i] + k0, &B3s[i * 256 + wid * 64]);
    }
    __syncthreads();
#pragma unroll
    for (int ks = 0; ks < 2; ++ks) {
      const int kg = ks * 4 + (lane >> 4);
      short8 af[4], b1f[2], b3f[2];
#pragma unroll
      for (int m = 0; m < 4; ++m) {
        int row = wm * 64 + m * 16 + (lane & 15);
        af[m] = As[row * 8 + (kg ^ (row & 7))];
      }
#pragma unroll
      for (int n = 0; n < 2; ++n) {
        int row = wn * 32 + n * 16 + (lane & 15);
        int base = row * 16;
        int sw = row & 15;
        float4 u0 = B1s[base + ((2 * kg) ^ sw)];
        float4 u1 = B1s[base + ((2 * kg + 1) ^ sw)];
        b1f[n] = pack8(u0, u1);
        float4 v0 = B3s[base + ((2 * kg) ^ sw)];
        float4 v1 = B3s[base + ((2 * kg + 1) ^ sw)];
        b3f[n] = pack8(v0, v1);
      }
#pragma unroll
      for (int m = 0; m < 4; ++m)
#pragma unroll
        for (int n = 0; n < 2; ++n) {
          acc1[m][n] = __builtin_amdgcn_mfma_f32_16x16x32_bf16(af[m], b1f[n], acc1[m][n], 0, 0, 0);
          acc3[m][n] = __builtin_amdgcn_mfma_f32_16x16x32_bf16(af[m], b3f[n], acc3[m][n], 0, 0, 0);
        }
    }
    __syncthreads();
  }

  const int obase = offs[e];
#pragma unroll
  for (int m = 0; m < 4; ++m)
#pragma unroll
    for (int r = 0; r < 4; ++r) {
      int i = my * 128 + wm * 64 + m * 16 + (lane >> 4) * 4 + r;
      if (i < n_e) {
        unsigned short* hp = h + (size_t)(obase + i) * INNER + n0 + wn * 32 + (lane & 15);
#pragma unroll
        for (int n = 0; n < 2; ++n) {
          float v1 = acc1[m][n][r];
          float v3 = acc3[m][n][r];
          float hv = __fdividef(v1, 1.f + __expf(-v1)) * v3;
          hp[n * 16] = f2bf(hv);
        }
      }
    }
}

// ------- GEMM2 (bf16 w2 from gemm1's fused cvt): out[t] += wt*(h·w2^T) ------
// R5-verified: 128x128, BK=64, 4 waves (2x2), single-buffer 2-barrier,
// XCD-bijective remap, 32KB LDS.
__global__ void __launch_bounds__(256, 3)
gemm2_bf(const unsigned short* __restrict__ h, const unsigned short* __restrict__ w2b,
         const int* __restrict__ cnt, const int* __restrict__ offs,
         const int* __restrict__ tok, const float* __restrict__ twt,
         float* __restrict__ out) {
  const int NWG   = (DIMSZ / 128) * NEXP * 16;   // 2048
  const int CHUNK = NWG / 8;
  const int lid = (blockIdx.x & 7) * CHUNK + (blockIdx.x >> 3);
  const int my = lid & 15;
  const int e  = (lid >> 4) & 7;
  const int bx = lid >> 7;             // 0..15
  const int n_e = cnt[e];
  if (n_e == 0 || my * 128 >= n_e) return;
  const int n0 = bx * 128;
  const int tid = threadIdx.x;
  const int lane = tid & 63;
  const int wid = tid >> 6;
  const int wm = wid >> 1, wn = wid & 1;
  const int obase = offs[e];

  __shared__ short8 As[1024];
  __shared__ short8 Bs[1024];

  const unsigned short* aptr[4];
#pragma unroll
  for (int i = 0; i < 4; ++i) {
    int sl = i * 256 + wid * 64 + lane;
    int row = sl >> 3, g = sl & 7;
    int ri = my * 128 + row; if (ri >= n_e) ri = n_e - 1;
    aptr[i] = h + (size_t)(obase + ri) * INNER + ((g ^ (row & 7)) * 8);
  }
  const unsigned short* bptr[4];
#pragma unroll
  for (int i = 0; i < 4; ++i) {
    int sl = i * 256 + wid * 64 + lane;
    int row = sl >> 3, g = sl & 7;
    bptr[i] = w2b + (size_t)e * DIMSZ * INNER + (size_t)(n0 + row) * INNER + (g ^ (row & 7)) * 8;
  }

  f32x4 acc[4][4] = {};

  for (int k0 = 0; k0 < INNER; k0 += 64) {
#pragma unroll
    for (int i = 0; i < 4; ++i) {
      gload16(aptr[i] + k0, &As[i * 256 + wid * 64]);
      gload16(bptr[i] + k0, &Bs[i * 256 + wid * 64]);
    }
    __syncthreads();
#pragma unroll
    for (int ks = 0; ks < 2; ++ks) {
      const int kg = ks * 4 + (lane >> 4);
      short8 af[4], bf[4];
#pragma unroll
      for (int m = 0; m < 4; ++m) {
        int row = wm * 64 + m * 16 + (lane & 15);
        af[m] = As[row * 8 + (kg ^ (row & 7))];
      }
#pragma unroll
      for (int n = 0; n < 4; ++n) {
        int row = wn * 64 + n * 16 + (lane & 15);
        bf[n] = Bs[row * 8 + (kg ^ (row & 7))];
      }
#pragma unroll
      for (int m = 0; m < 4; ++m)
#pragma unroll
        for (int n = 0; n < 4; ++n)
          acc[m][n] = __builtin_amdgcn_mfma_f32_16x16x32_bf16(af[m], bf[n], acc[m][n], 0, 0, 0);
    }
    __syncthreads();
  }

#pragma unroll
  for (int m = 0; m < 4; ++m)
#pragma unroll
    for (int r = 0; r < 4; ++r) {
      int i = my * 128 + wm * 64 + m * 16 + (lane >> 4) * 4 + r;
      if (i < n_e) {
        int t = tok[e * TOKS + i];
        float wt = twt[e * TOKS + i];
        float* op = out + (size_t)t * DIMSZ + n0 + wn * 64 + (lane & 15);
#pragma unroll
        for (int n = 0; n < 4; ++n)
          atomicAdd(op + n * 16, acc[m][n][r] * wt);
      }
    }
}

// ======= fallback path (fp32 weights, reg-staged cvt) — used if ws small ====
__global__ void __launch_bounds__(256, 2)
gemm1_f32(const unsigned short* __restrict__ xbf,
          const float* __restrict__ w1, const float* __restrict__ w3,
          const int* __restrict__ cnt, const int* __restrict__ offs,
          const int* __restrict__ tok, unsigned short* __restrict__ h) {
  const int e = blockIdx.z;
  const int n_e = cnt[e];
  const int by = blockIdx.y;
  if (n_e == 0 || by * 128 >= n_e) return;
  const int n0 = blockIdx.x * 128;
  const int tid = threadIdx.x;
  const int lane = tid & 63;
  const int wid = tid >> 6;
  const int wm = wid >> 1, wn = wid & 1;

  __shared__ short8 As[1024];
  __shared__ short8 B1s[1024];
  __shared__ short8 B3s[1024];

  const unsigned short* asrc[4];
  int adst[4];
#pragma unroll
  for (int rep = 0; rep < 4; ++rep) {
    int flat = rep * 256 + tid;
    int row = flat >> 3, g = flat & 7;
    int ri = by * 128 + row;
    if (ri >= n_e) ri = n_e - 1;
    int tkn = tok[e * TOKS + ri];
    asrc[rep] = xbf + (size_t)tkn * DIMSZ + g * 8;
    adst[rep] = row * 8 + (g ^ (row & 7));
  }
  const float* w1e = w1 + (size_t)e * INNER * DIMSZ;
  const float* w3e = w3 + (size_t)e * INNER * DIMSZ;
  const float* b1src[2]; const float* b3src[2];
  int bd0[2], bd1[2];
#pragma unroll
  for (int rep = 0; rep < 2; ++rep) {
    int row = rep * 64 + (tid >> 2);
    int gb = (tid & 3) * 2;
    b1src[rep] = w1e + (size_t)(n0 + row) * DIMSZ + gb * 8;
    b3src[rep] = w3e + (size_t)(n0 + row) * DIMSZ + gb * 8;
    bd0[rep] = row * 8 + (gb ^ (row & 7));
    bd1[rep] = row * 8 + ((gb + 1) ^ (row & 7));
  }

  f32x4 acc1[4][4] = {};
  f32x4 acc3[4][4] = {};

#pragma unroll 1
  for (int k0 = 0; k0 < DIMSZ; k0 += 64) {
#pragma unroll
    for (int rep = 0; rep < 4; ++rep)
      As[adst[rep]] = *(const short8*)(asrc[rep] + k0);
#pragma unroll
    for (int rep = 0; rep < 2; ++rep) {
      const float4* p = (const float4*)(b1src[rep] + k0);
      float4 a0 = p[0], a1 = p[1], a2 = p[2], a3 = p[3];
      B1s[bd0[rep]] = pack8(a0, a1);
      B1s[bd1[rep]] = pack8(a2, a3);
      const float4* q = (const float4*)(b3src[rep] + k0);
      float4 c0 = q[0], c1 = q[1], c2 = q[2], c3 = q[3];
      B3s[bd0[rep]] = pack8(c0, c1);
      B3s[bd1[rep]] = pack8(c2, c3);
    }
    __syncthreads();
#pragma unroll
    for (int ks = 0; ks < 2; ++ks) {
      const int kg = ks * 4 + (lane >> 4);
      short8 af[4], b1f[4], b3f[4];
#pragma unroll
      for (int m = 0; m < 4; ++m) {
        int row = wm * 64 + m * 16 + (lane & 15);
        af[m] = As[row * 8 + (kg ^ (row & 7))];
      }
#pragma unroll
      for (int n = 0; n < 4; ++n) {
        int row = wn * 64 + n * 16 + (lane & 15);
        int idx = row * 8 + (kg ^ (row & 7));
        b1f[n] = B1s[idx];
        b3f[n] = B3s[idx];
      }
#pragma unroll
      for (int m = 0; m < 4; ++m)
#pragma unroll
        for (int n = 0; n < 4; ++n) {
          acc1[m][n] = __builtin_amdgcn_mfma_f32_16x16x32_bf16(af[m], b1f[n], acc1[m][n], 0, 0, 0);
          acc3[m][n] = __builtin_amdgcn_mfma_f32_16x16x32_bf16(af[m], b3f[n], acc3[m][n], 0, 0, 0);
        }
    }
    __syncthreads();
  }

  const int obase = offs[e];
#pragma unroll
  for (int m = 0; m < 4; ++m)
#pragma unroll
    for (int r = 0; r < 4; ++r) {
      int i = by * 128 + wm * 64 + m * 16 + (lane >> 4) * 4 + r;
      if (i < n_e) {
        unsigned short* hp = h + (size_t)(obase + i) * INNER + n0 + wn * 64 + (lane & 15);
#pragma unroll
        for (int n = 0; n < 4; ++n) {
          float v1 = acc1[m][n][r];
          float v3 = acc3[m][n][r];
          float hv = __fdividef(v1, 1.f + __expf(-v1)) * v3;
          hp[n * 16] = f2bf(hv);
        }
      }
    }
}

__global__ void __launch_bounds__(256, 2)
gemm2_f32(const unsigned short* __restrict__ h, const float* __restrict__ w2,
          const int* __restrict__ cnt, const int* __restrict__ offs,
          const int* __restrict__ tok, const float* __restrict__ twt,
          float* __restrict__ out) {
  const int e = blockIdx.z;
  const int n_e = cnt[e];
  const int by = blockIdx.y;
  if (n_e == 0 || by * 128 >= n_e) return;
  const int n0 = blockIdx.x * 128;
  const int tid = threadIdx.x;
  const int lane = tid & 63;
  const int wid = tid >> 6;
  const int wm = wid >> 1, wn = wid & 1;
  const int obase = offs[e];

  __shared__ short8 As[1024];
  __shared__ short8 Bs[1024];

  const unsigned short* asrc[4];
  int adst[4];
#pragma unroll
  for (int rep = 0; rep < 4; ++rep) {
    int flat = rep * 256 + tid;
    int row = flat >> 3, g = flat & 7;
    int ri = by * 128 + row;
    if (ri >= n_e) ri = n_e - 1;
    asrc[rep] = h + (size_t)(obase + ri) * INNER + g * 8;
    adst[rep] = row * 8 + (g ^ (row & 7));
  }
  const float* w2e = w2 + (size_t)e * DIMSZ * INNER;
  const float* bsrc[2];
  int bd0[2], bd1[2];
#pragma unroll
  for (int rep = 0; rep < 2; ++rep) {
    int row = rep * 64 + (tid >> 2);
    int gb = (tid & 3) * 2;
    bsrc[rep] = w2e + (size_t)(n0 + row) * INNER + gb * 8;
    bd0[rep] = row * 8 + (gb ^ (row & 7));
    bd1[rep] = row * 8 + ((gb + 1) ^ (row & 7));
  }

  f32x4 acc[4][4] = {};

#pragma unroll 1
  for (int k0 = 0; k0 < INNER; k0 += 64) {
#pragma unroll
    for (int rep = 0; rep < 4; ++rep)
      As[adst[rep]] = *(const short8*)(asrc[rep] + k0);
#pragma unroll
    for (int rep = 0; rep < 2; ++rep) {
      const float4* p = (const float4*)(bsrc[rep] + k0);
      float4 a0 = p[0], a1 = p[1], a2 = p[2], a3 = p[3];
      Bs[bd0[rep]] = pack8(a0, a1);
      Bs[bd1[rep]] = pack8(a2, a3);
    }
    __syncthreads();
#pragma unroll
    for (int ks = 0; ks < 2; ++ks) {
      const int kg = ks * 4 + (lane >> 4);
      short8 af[4], bf[4];
#pragma unroll
      for (int m = 0; m < 4; ++m) {
        int row = wm * 64 + m * 16 + (lane & 15);
        af[m] = As[row * 8 + (kg ^ (row & 7))];
      }
#pragma unroll
      for (int n = 0; n < 4; ++n) {
        int row = wn * 64 + n * 16 + (lane & 15);
        bf[n] = Bs[row * 8 + (kg ^ (row & 7))];
      }
#pragma unroll
      for (int m = 0; m < 4; ++m)
#pragma unroll
        for (int n = 0; n < 4; ++n)
          acc[m][n] = __builtin_amdgcn_mfma_f32_16x16x32_bf16(af[m], bf[n], acc[m][n], 0, 0, 0);
    }
    __syncthreads();
  }

#pragma unroll
  for (int m = 0; m < 4; ++m)
#pragma unroll
    for (int r = 0; r < 4; ++r) {
      int i = by * 128 + wm * 64 + m * 16 + (lane >> 4) * 4 + r;
      if (i < n_e) {
        int t = tok[e * TOKS + i];
        float wt = twt[e * TOKS + i];
        float* op = out + (size_t)t * DIMSZ + n0 + wn * 64 + (lane & 15);
#pragma unroll
        for (int n = 0; n < 4; ++n)
          atomicAdd(op + n * 16, acc[m][n][r] * wt);
      }
    }
}

// ---------------------------------------------------------------------------
extern "C" void kernel_launch(void* const* d_in, const int* in_sizes, int n_in,
                              void* d_out, int out_size, void* d_ws, size_t ws_size,
                              hipStream_t stream) {
  (void)in_sizes; (void)n_in;
  const float* x  = (const float*)d_in[0];
  const float* gw = (const float*)d_in[1];
  const float* w1 = (const float*)d_in[2];
  const float* w2 = (const float*)d_in[3];
  const float* w3 = (const float*)d_in[4];
  float* out = (float*)d_out;

  char* ws = (char*)d_ws;
  int*            sel  = (int*)(ws);
  float*          wts  = (float*)(ws + (16 << 10));
  int*            cnt  = (int*)(ws + (32 << 10));
  int*            offs = (int*)(ws + (32 << 10) + 64);
  int*            tok  = (int*)(ws + (33 << 10));
  float*          twt  = (float*)(ws + (97 << 10));
  unsigned short* xbf  = (unsigned short*)(ws + (1 << 20));   // 8.4 MB
  unsigned short* h    = (unsigned short*)(ws + (16 << 20));  // 46.2 MB

  const size_t WB = (size_t)NEXP * INNER * DIMSZ * 2;         // 184,549,376 B
  unsigned short* w2bf = (unsigned short*)(ws + (64ull << 20));
  const size_t NEED = (64ull << 20) + WB;                     // ~249 MB

  hipMemsetAsync(out, 0, (size_t)out_size * sizeof(float), stream);
  cvtx_kernel<<<2048, 256, 0, stream>>>(x, xbf);
  router_kernel<<<TOKS, 64, 0, stream>>>(x, gw, sel, wts);
  compact_kernel<<<1, 512, 0, stream>>>(sel, wts, cnt, offs, tok, twt);

  if (ws_size >= NEED) {
    // gemm1 grid = GEMM blocks + 2048 tail blocks doing w2 fp32->bf16
    gemm1_fw<<<(INNER / 64) * 16 * NEXP + 2048, 256, 0, stream>>>(
        xbf, w1, w3, w2, w2bf, cnt, offs, tok, h);
    gemm2_bf<<<(DIMSZ / 128) * 16 * NEXP, 256, 0, stream>>>(
        h, w2bf, cnt, offs, tok, twt, out);
  } else {
    gemm1_f32<<<dim3(INNER / 128, TOKS / 128, NEXP), 256, 0, stream>>>(
        xbf, w1, w3, cnt, offs, tok, h);
    gemm2_f32<<<dim3(DIMSZ / 128, TOKS / 128, NEXP), 256, 0, stream>>>(
        h, w2, cnt, offs, tok, twt, out);
  }
}

// Round 8
// 709.948 us; speedup vs baseline: 1.3786x; 1.0701x over previous
//
#include <hip/hip_runtime.h>
#include <hip/hip_bf16.h>
#include <cstdint>
#include <cstddef>

// MoE: T=2048 tokens, D=2048, INNER=5632, E=8, top-2 routing (sparse == dense ref).

#define TOKS  2048
#define DIMSZ 2048
#define INNER 5632
#define NEXP  8

typedef __attribute__((ext_vector_type(8))) short short8;
typedef __attribute__((ext_vector_type(4))) float f32x4;

__device__ __forceinline__ unsigned short f2bf(float f) {
  __hip_bfloat16 b = __float2bfloat16(f);
  return __builtin_bit_cast(unsigned short, b);
}

__device__ __forceinline__ short8 pack8(float4 a, float4 b) {
  short8 s;
  s[0] = (short)f2bf(a.x); s[1] = (short)f2bf(a.y);
  s[2] = (short)f2bf(a.z); s[3] = (short)f2bf(a.w);
  s[4] = (short)f2bf(b.x); s[5] = (short)f2bf(b.y);
  s[6] = (short)f2bf(b.z); s[7] = (short)f2bf(b.w);
  return s;
}

// async global->LDS, 16B/lane; dst is wave-uniform base (HW adds lane*16)
__device__ __forceinline__ void gload16(const unsigned short* src, short8* dst) {
  __builtin_amdgcn_global_load_lds(
      (const __attribute__((address_space(1))) void*)src,
      (__attribute__((address_space(3))) void*)dst, 16, 0, 0);
}
__device__ __forceinline__ void gload16f(const float* src, float4* dst) {
  __builtin_amdgcn_global_load_lds(
      (const __attribute__((address_space(1))) void*)src,
      (__attribute__((address_space(3))) void*)dst, 16, 0, 0);
}

// ---------------- router -----------------------------------------------------
__global__ void __launch_bounds__(64)
router_kernel(const float* __restrict__ x, const float* __restrict__ gw,
              int* __restrict__ sel, float* __restrict__ wts) {
  const int t = blockIdx.x;
  const int l = threadIdx.x;
  const float* xr = x + (size_t)t * DIMSZ;
  float xv[32];
#pragma unroll
  for (int i = 0; i < 32; ++i) xv[i] = xr[l + 64 * i];
  float lg[NEXP];
#pragma unroll
  for (int e = 0; e < NEXP; ++e) {
    const float* gr = gw + e * DIMSZ;
    float s = 0.f;
#pragma unroll
    for (int i = 0; i < 32; ++i) s += xv[i] * gr[l + 64 * i];
#pragma unroll
    for (int off = 32; off > 0; off >>= 1) s += __shfl_down(s, off, 64);
    lg[e] = s;
  }
  if (l == 0) {
    float m = lg[0];
#pragma unroll
    for (int e = 1; e < NEXP; ++e) m = fmaxf(m, lg[e]);
    float p[NEXP];
#pragma unroll
    for (int e = 0; e < NEXP; ++e) p[e] = __expf(lg[e] - m);
    int i1 = 0;
#pragma unroll
    for (int e = 1; e < NEXP; ++e) if (p[e] > p[i1]) i1 = e;
    int i2 = (i1 == 0) ? 1 : 0;
#pragma unroll
    for (int e = 0; e < NEXP; ++e) if (e != i1 && p[e] > p[i2]) i2 = e;
    float den = p[i1] + p[i2];
    sel[2 * t] = i1; sel[2 * t + 1] = i2;
    wts[2 * t] = p[i1] / den; wts[2 * t + 1] = p[i2] / den;
  }
}

// ---- compaction -------------------------------------------------------------
__global__ void __launch_bounds__(512)
compact_kernel(const int* __restrict__ sel, const float* __restrict__ wts,
               int* __restrict__ cnt, int* __restrict__ offs,
               int* __restrict__ tok, float* __restrict__ twt) {
  const int w = threadIdx.x >> 6;
  const int l = threadIdx.x & 63;
  int c = 0;
  for (int base = 0; base < 2 * TOKS; base += 64) {
    int s = base + l;
    bool m = (sel[s] == w);
    unsigned long long mask = __ballot(m);
    int pre = __popcll(mask & ((1ull << l) - 1ull));
    if (m) {
      tok[w * TOKS + c + pre] = s >> 1;
      twt[w * TOKS + c + pre] = wts[s];
    }
    c += __popcll(mask);
  }
  if (l == 0) cnt[w] = c;
  __syncthreads();
  if (threadIdx.x == 0) {
    int acc = 0;
    for (int e = 0; e < NEXP; ++e) { offs[e] = acc; acc += cnt[e]; }
  }
}

// ---------------- x fp32 -> bf16 ---------------------------------------------
__global__ void __launch_bounds__(256)
cvtx_kernel(const float* __restrict__ x, unsigned short* __restrict__ xbf) {
  const int i = blockIdx.x * 256 + threadIdx.x;
  const float4* src = (const float4*)x;
  ((short8*)xbf)[i] = pack8(src[2 * i], src[2 * i + 1]);
}

// ------- GEMM1 (direct fp32 weights): h = silu(x·w1^T) * (x·w3^T) -----------
// 128(M)x64(N), BK=64, 4 waves (2Mx2N). R7-proven m97 single-buffer 2-barrier
// loop + XCD-bijective remap + fp32 B staged via global_load_lds with
// in-fragment cvt. NEW vs R7: w2->bf16 conversion blocks are INTERLEAVED
// through the per-XCD dispatch order (2 of every 13 slots) so their BW work
// hides under the GEMM's HBM slack instead of serializing at the end.
__global__ void __launch_bounds__(256, 3)
gemm1_fw(const unsigned short* __restrict__ xbf,
         const float* __restrict__ w1, const float* __restrict__ w3,
         const float* __restrict__ w2, unsigned short* __restrict__ w2bf,
         const int* __restrict__ cnt, const int* __restrict__ offs,
         const int* __restrict__ tok, unsigned short* __restrict__ h) {
  const int tid = threadIdx.x;
  // per-XCD slot decode: bid -> (xcd, slot); 1664 slots/XCD; slot%13>=11 -> cvt
  const int xcd = blockIdx.x & 7;
  const int s   = blockIdx.x >> 3;          // 0..1663
  const int q13 = s / 13, r13 = s % 13;

  if (r13 >= 11) {                          // ---- interleaved w2 fp32->bf16 --
    const int idx = xcd * 256 + q13 * 2 + (r13 - 11);   // 0..2047
    const int n8 = (int)(((size_t)NEXP * DIMSZ * INNER) / 8);  // 11,534,336
    for (int i = idx * 256 + tid; i < n8; i += 2048 * 256) {
      const float4* sp = (const float4*)w2 + 2 * (size_t)i;
      ((short8*)w2bf)[i] = pack8(sp[0], sp[1]);
    }
    return;
  }

  // GEMM slot: contiguous panel-major run within this XCD
  const int lid = xcd * 1408 + q13 * 11 + r13;   // 0..11263
  const int my = lid & 15;             // M-slot (panel-mates adjacent in lid)
  const int e  = (lid >> 4) & 7;
  const int bx = lid >> 7;             // 0..87 N-panel
  const int n_e = cnt[e];
  if (n_e == 0 || my * 128 >= n_e) return;
  const int n0 = bx * 64;
  const int lane = tid & 63;
  const int wid = tid >> 6;
  const int wm = wid >> 1, wn = wid & 1;

  __shared__ short8 As[1024];    // 128 rows x 8 bf16-groups (16KB)
  __shared__ float4 B1s[1024];   // 64 rows x 16 f32-groups (16KB)
  __shared__ float4 B3s[1024];   // total 48KB -> 3 blocks/CU

  // A: per-lane pre-swizzled source (g ^ row&7), linear LDS dest
  const unsigned short* aptr[4];
#pragma unroll
  for (int i = 0; i < 4; ++i) {
    int sl = i * 256 + wid * 64 + lane;
    int row = sl >> 3, g = sl & 7;
    int ri = my * 128 + row; if (ri >= n_e) ri = n_e - 1;
    int tkn = tok[e * TOKS + ri];
    aptr[i] = xbf + (size_t)tkn * DIMSZ + ((g ^ (row & 7)) * 8);
  }
  // B fp32: 64 rows x 16 groups of 4 floats; source col-group = gg ^ (row&15)
  const float* b1p[4]; const float* b3p[4];
#pragma unroll
  for (int i = 0; i < 4; ++i) {
    int sl = i * 256 + wid * 64 + lane;
    int row = sl >> 4, gg = sl & 15;
    size_t off = (size_t)e * INNER * DIMSZ + (size_t)(n0 + row) * DIMSZ
               + ((gg ^ (row & 15)) * 4);
    b1p[i] = w1 + off;
    b3p[i] = w3 + off;
  }

  f32x4 acc1[4][2] = {};
  f32x4 acc3[4][2] = {};

  for (int k0 = 0; k0 < DIMSZ; k0 += 64) {
#pragma unroll
    for (int i = 0; i < 4; ++i) gload16(aptr[i] + k0, &As[i * 256 + wid * 64]);
#pragma unroll
    for (int i = 0; i < 4; ++i) {
      gload16f(b1p[i] + k0, &B1s[i * 256 + wid * 64]);
      gload16f(b3p[i] + k0, &B3s[i * 256 + wid * 64]);
    }
    __syncthreads();
#pragma unroll
    for (int ks = 0; ks < 2; ++ks) {
      const int kg = ks * 4 + (lane >> 4);
      short8 af[4], b1f[2], b3f[2];
#pragma unroll
      for (int m = 0; m < 4; ++m) {
        int row = wm * 64 + m * 16 + (lane & 15);
        af[m] = As[row * 8 + (kg ^ (row & 7))];
      }
#pragma unroll
      for (int n = 0; n < 2; ++n) {
        int row = wn * 32 + n * 16 + (lane & 15);
        int base = row * 16;
        int sw = row & 15;
        float4 u0 = B1s[base + ((2 * kg) ^ sw)];
        float4 u1 = B1s[base + ((2 * kg + 1) ^ sw)];
        b1f[n] = pack8(u0, u1);
        float4 v0 = B3s[base + ((2 * kg) ^ sw)];
        float4 v1 = B3s[base + ((2 * kg + 1) ^ sw)];
        b3f[n] = pack8(v0, v1);
      }
#pragma unroll
      for (int m = 0; m < 4; ++m)
#pragma unroll
        for (int n = 0; n < 2; ++n) {
          acc1[m][n] = __builtin_amdgcn_mfma_f32_16x16x32_bf16(af[m], b1f[n], acc1[m][n], 0, 0, 0);
          acc3[m][n] = __builtin_amdgcn_mfma_f32_16x16x32_bf16(af[m], b3f[n], acc3[m][n], 0, 0, 0);
        }
    }
    __syncthreads();
  }

  const int obase = offs[e];
#pragma unroll
  for (int m = 0; m < 4; ++m)
#pragma unroll
    for (int r = 0; r < 4; ++r) {
      int i = my * 128 + wm * 64 + m * 16 + (lane >> 4) * 4 + r;
      if (i < n_e) {
        unsigned short* hp = h + (size_t)(obase + i) * INNER + n0 + wn * 32 + (lane & 15);
#pragma unroll
        for (int n = 0; n < 2; ++n) {
          float v1 = acc1[m][n][r];
          float v3 = acc3[m][n][r];
          float hv = __fdividef(v1, 1.f + __expf(-v1)) * v3;
          hp[n * 16] = f2bf(hv);
        }
      }
    }
}

// ------- GEMM2 (bf16 w2): out[t] += wt * (h · w2^T) -------------------------
// NEW: 256(M)x128(N), BK=64, 512 thr / 8 waves (4Mx2N, 64x64 each).
// Same proven single-buffer 2-barrier loop; halves w2 M-passes (2 vs 4).
// LDS 48KB; launch_bounds(512,4) -> 2 blocks/CU = 16 waves/CU.
__global__ void __launch_bounds__(512, 4)
gemm2_bf(const unsigned short* __restrict__ h, const unsigned short* __restrict__ w2b,
         const int* __restrict__ cnt, const int* __restrict__ offs,
         const int* __restrict__ tok, const float* __restrict__ twt,
         float* __restrict__ out) {
  const int NWG   = (DIMSZ / 128) * NEXP * 8;    // 1024
  const int CHUNK = NWG / 8;                     // 128
  const int lid = (blockIdx.x & 7) * CHUNK + (blockIdx.x >> 3);
  const int my = lid & 7;              // M-slot (256 rows each)
  const int e  = (lid >> 3) & 7;
  const int bx = lid >> 6;             // 0..15
  const int n_e = cnt[e];
  if (n_e == 0 || my * 256 >= n_e) return;
  const int n0 = bx * 128;
  const int tid = threadIdx.x;
  const int lane = tid & 63;
  const int wid = tid >> 6;
  const int wm = wid >> 1, wn = wid & 1;   // wm 0..3, wn 0..1
  const int obase = offs[e];

  __shared__ short8 As[2048];   // 256 rows x 8 groups (32KB)
  __shared__ short8 Bs[1024];   // 128 rows x 8 groups (16KB)

  const unsigned short* aptr[4];
#pragma unroll
  for (int i = 0; i < 4; ++i) {
    int sl = i * 512 + wid * 64 + lane;
    int row = sl >> 3, g = sl & 7;
    int ri = my * 256 + row; if (ri >= n_e) ri = n_e - 1;
    aptr[i] = h + (size_t)(obase + ri) * INNER + ((g ^ (row & 7)) * 8);
  }
  const unsigned short* bptr[2];
#pragma unroll
  for (int i = 0; i < 2; ++i) {
    int sl = i * 512 + wid * 64 + lane;
    int row = sl >> 3, g = sl & 7;
    bptr[i] = w2b + (size_t)e * DIMSZ * INNER + (size_t)(n0 + row) * INNER + (g ^ (row & 7)) * 8;
  }

  f32x4 acc[4][4] = {};

  for (int k0 = 0; k0 < INNER; k0 += 64) {
#pragma unroll
    for (int i = 0; i < 4; ++i) gload16(aptr[i] + k0, &As[i * 512 + wid * 64]);
#pragma unroll
    for (int i = 0; i < 2; ++i) gload16(bptr[i] + k0, &Bs[i * 512 + wid * 64]);
    __syncthreads();
#pragma unroll
    for (int ks = 0; ks < 2; ++ks) {
      const int kg = ks * 4 + (lane >> 4);
      short8 af[4], bf[4];
#pragma unroll
      for (int m = 0; m < 4; ++m) {
        int row = wm * 64 + m * 16 + (lane & 15);
        af[m] = As[row * 8 + (kg ^ (row & 7))];
      }
#pragma unroll
      for (int n = 0; n < 4; ++n) {
        int row = wn * 64 + n * 16 + (lane & 15);
        bf[n] = Bs[row * 8 + (kg ^ (row & 7))];
      }
#pragma unroll
      for (int m = 0; m < 4; ++m)
#pragma unroll
        for (int n = 0; n < 4; ++n)
          acc[m][n] = __builtin_amdgcn_mfma_f32_16x16x32_bf16(af[m], bf[n], acc[m][n], 0, 0, 0);
    }
    __syncthreads();
  }

#pragma unroll
  for (int m = 0; m < 4; ++m)
#pragma unroll
    for (int r = 0; r < 4; ++r) {
      int i = my * 256 + wm * 64 + m * 16 + (lane >> 4) * 4 + r;
      if (i < n_e) {
        int t = tok[e * TOKS + i];
        float wt = twt[e * TOKS + i];
        float* op = out + (size_t)t * DIMSZ + n0 + wn * 64 + (lane & 15);
#pragma unroll
        for (int n = 0; n < 4; ++n)
          atomicAdd(op + n * 16, acc[m][n][r] * wt);
      }
    }
}

// ---------------------------------------------------------------------------
extern "C" void kernel_launch(void* const* d_in, const int* in_sizes, int n_in,
                              void* d_out, int out_size, void* d_ws, size_t ws_size,
                              hipStream_t stream) {
  (void)in_sizes; (void)n_in; (void)ws_size;
  const float* x  = (const float*)d_in[0];
  const float* gw = (const float*)d_in[1];
  const float* w1 = (const float*)d_in[2];
  const float* w2 = (const float*)d_in[3];
  const float* w3 = (const float*)d_in[4];
  float* out = (float*)d_out;

  char* ws = (char*)d_ws;
  int*            sel  = (int*)(ws);
  float*          wts  = (float*)(ws + (16 << 10));
  int*            cnt  = (int*)(ws + (32 << 10));
  int*            offs = (int*)(ws + (32 << 10) + 64);
  int*            tok  = (int*)(ws + (33 << 10));
  float*          twt  = (float*)(ws + (97 << 10));
  unsigned short* xbf  = (unsigned short*)(ws + (1 << 20));   // 8.4 MB
  unsigned short* h    = (unsigned short*)(ws + (16 << 20));  // 46.2 MB
  unsigned short* w2bf = (unsigned short*)(ws + (64ull << 20));  // 184.5 MB

  hipMemsetAsync(out, 0, (size_t)out_size * sizeof(float), stream);
  cvtx_kernel<<<2048, 256, 0, stream>>>(x, xbf);
  router_kernel<<<TOKS, 64, 0, stream>>>(x, gw, sel, wts);
  compact_kernel<<<1, 512, 0, stream>>>(sel, wts, cnt, offs, tok, twt);

  // gemm1: 11264 GEMM blocks + 2048 interleaved w2-cvt blocks = 13312
  gemm1_fw<<<13312, 256, 0, stream>>>(
      xbf, w1, w3, w2, w2bf, cnt, offs, tok, h);
  gemm2_bf<<<(DIMSZ / 128) * NEXP * 8, 512, 0, stream>>>(
      h, w2bf, cnt, offs, tok, twt, out);
}